// Round 9
// baseline (85722.491 us; speedup 1.0000x reference)
//
#include <hip/hip_runtime.h>
#include <cstddef>

#define NSTEP 4096
// Pin a named float4 variable into VGPRs (unrematerializable asm-defined SSA).
#define PIN4(v) asm volatile("" : "+v"((v).x), "+v"((v).y), "+v"((v).z), "+v"((v).w))
#define FMA4(W,V,A) { (A)=fmaf((W).x,(V).x,(A)); (A)=fmaf((W).y,(V).y,(A)); (A)=fmaf((W).z,(V).z,(A)); (A)=fmaf((W).w,(V).w,(A)); }

// ===================== BatchNorm over timestep channels =====================
__global__ __launch_bounds__(256) void bn_kernel(const float* __restrict__ x,
                                                 const float* __restrict__ bn_w,
                                                 const float* __restrict__ bn_b,
                                                 float* __restrict__ xn)
{
  const int t   = blockIdx.x;        // 0..1023
  const int tid = threadIdx.x;       // 256 = B*F
  const int b   = tid >> 6;
  const int f   = tid & 63;
  const float v = x[((size_t)b * 1024 + t) * 64 + f];
  float s = v, ss = v * v;
  #pragma unroll
  for (int off = 32; off > 0; off >>= 1) {
    s  += __shfl_down(s, off);
    ss += __shfl_down(ss, off);
  }
  __shared__ float sh[8];
  const int w = tid >> 6;
  if ((tid & 63) == 0) { sh[w] = s; sh[4 + w] = ss; }
  __syncthreads();
  const float S    = sh[0] + sh[1] + sh[2] + sh[3];
  const float SS   = sh[4] + sh[5] + sh[6] + sh[7];
  const float mean = S * (1.0f / 256.0f);
  const float var  = SS * (1.0f / 256.0f) - mean * mean;  // biased, matches jnp.var
  const float inv  = rsqrtf(var + 1e-5f);
  const float scale = bn_w[t] * inv;
  const float shift = bn_b[t] - mean * scale;
  xn[((size_t)b * 1024 + t) * 64 + f] = v * scale + shift;
}

// ===================== grid barrier (proven rounds 4-8) =====================
template<int NBLK>
__device__ __forceinline__ void grid_barrier(unsigned* __restrict__ bar,
                                             unsigned step1, int tid)
{
  constexpr unsigned GSZ = NBLK / 8;
  __syncthreads();
  if (tid == 0) {
    unsigned* gcnt = bar + 16 + 16 * (blockIdx.x / GSZ);
    unsigned* root = bar;
    __builtin_amdgcn_fence(__ATOMIC_RELEASE, "agent");
    const unsigned a = __hip_atomic_fetch_add(gcnt, 1u, __ATOMIC_RELAXED,
                                              __HIP_MEMORY_SCOPE_AGENT);
    if (a == step1 * GSZ - 1u)
      __hip_atomic_fetch_add(root, 1u, __ATOMIC_RELAXED, __HIP_MEMORY_SCOPE_AGENT);
    const unsigned tgt = step1 * 8u;
    while (__hip_atomic_load(root, __ATOMIC_RELAXED, __HIP_MEMORY_SCOPE_AGENT) < tgt)
      __builtin_amdgcn_s_sleep(2);
    __builtin_amdgcn_fence(__ATOMIC_ACQUIRE, "agent");
  }
  __syncthreads();
}

// ===================== wave helpers =========================================
__device__ __forceinline__ void reduce4(float& a0, float& a1, float& a2, float& a3)
{
  #pragma unroll
  for (int off = 32; off; off >>= 1) {
    a0 += __shfl_xor(a0, off);
    a1 += __shfl_xor(a1, off);
    a2 += __shfl_xor(a2, off);
    a3 += __shfl_xor(a3, off);
  }
}

// bs = (b_i, b_f, b_g, b_o); a0..a3 = gate pre-activations (i,f,g,o)
__device__ __forceinline__ float lstm_act4(float a0, float a1, float a2, float a3,
                                           float4 bs, float& c)
{
  const float ig = 1.0f / (1.0f + expf(-(a0 + bs.x)));
  const float fg = 1.0f / (1.0f + expf(-(a1 + bs.y)));
  const float og = 1.0f / (1.0f + expf(-(a3 + bs.w)));
  const float gt = tanhf(a2 + bs.z);
  c = fg * c + ig * gt;
  return og * tanhf(c);
}

// ===================== Layer 1: weights in NAMED registers ==================
// Per wave (one h-unit): w_ih = 1 float/gate (float4 wi), w_hh = 8 float4/gate.
#define L1J(j) { const float4 v = hr[(j)*64 + lane]; \
  FMA4(h0##j, v, a0); FMA4(h1##j, v, a1); FMA4(h2##j, v, a2); FMA4(h3##j, v, a3); }

__global__ __launch_bounds__(512, 1)
void lstm_l1(const float* __restrict__ win, const float* __restrict__ whh,
             const float* __restrict__ bih, const float* __restrict__ bhh,
             const float* __restrict__ X,     // (4096,64) normalized input
             float* __restrict__ Hout,        // (4097,2048), row r = h(r-1)
             unsigned* __restrict__ bar)
{
  constexpr int H = 2048;
  const int tid = threadIdx.x, lane = tid & 63, wsl = tid >> 6;
  const int hid = blockIdx.x * 8 + wsl;       // 2048 waves == H

  const size_t r0 = (size_t)0 * H + hid, r1 = (size_t)1 * H + hid,
               r2 = (size_t)2 * H + hid, r3 = (size_t)3 * H + hid;
  float4 wi = make_float4(win[r0 * 64 + lane], win[r1 * 64 + lane],
                          win[r2 * 64 + lane], win[r3 * 64 + lane]);
  PIN4(wi);
  const float4* p0 = (const float4*)(whh + r0 * H);
  const float4* p1 = (const float4*)(whh + r1 * H);
  const float4* p2 = (const float4*)(whh + r2 * H);
  const float4* p3 = (const float4*)(whh + r3 * H);
  float4 h00=p0[0*64+lane], h01=p0[1*64+lane], h02=p0[2*64+lane], h03=p0[3*64+lane],
         h04=p0[4*64+lane], h05=p0[5*64+lane], h06=p0[6*64+lane], h07=p0[7*64+lane];
  float4 h10=p1[0*64+lane], h11=p1[1*64+lane], h12=p1[2*64+lane], h13=p1[3*64+lane],
         h14=p1[4*64+lane], h15=p1[5*64+lane], h16=p1[6*64+lane], h17=p1[7*64+lane];
  float4 h20=p2[0*64+lane], h21=p2[1*64+lane], h22=p2[2*64+lane], h23=p2[3*64+lane],
         h24=p2[4*64+lane], h25=p2[5*64+lane], h26=p2[6*64+lane], h27=p2[7*64+lane];
  float4 h30=p3[0*64+lane], h31=p3[1*64+lane], h32=p3[2*64+lane], h33=p3[3*64+lane],
         h34=p3[4*64+lane], h35=p3[5*64+lane], h36=p3[6*64+lane], h37=p3[7*64+lane];
  PIN4(h00); PIN4(h01); PIN4(h02); PIN4(h03); PIN4(h04); PIN4(h05); PIN4(h06); PIN4(h07);
  PIN4(h10); PIN4(h11); PIN4(h12); PIN4(h13); PIN4(h14); PIN4(h15); PIN4(h16); PIN4(h17);
  PIN4(h20); PIN4(h21); PIN4(h22); PIN4(h23); PIN4(h24); PIN4(h25); PIN4(h26); PIN4(h27);
  PIN4(h30); PIN4(h31); PIN4(h32); PIN4(h33); PIN4(h34); PIN4(h35); PIN4(h36); PIN4(h37);
  float4 bs = make_float4(bih[r0] + bhh[r0], bih[r1] + bhh[r1],
                          bih[r2] + bhh[r2], bih[r3] + bhh[r3]);
  PIN4(bs);
  float c = 0.0f;

  #pragma unroll 1
  for (int t = 0; t < NSTEP; ++t) {
    const float xv = X[(size_t)t * 64 + lane];
    const float4* hr = (const float4*)(Hout + (size_t)t * H);   // h(t-1)
    float a0 = wi.x * xv, a1 = wi.y * xv, a2 = wi.z * xv, a3 = wi.w * xv;
    L1J(0) L1J(1) L1J(2) L1J(3) L1J(4) L1J(5) L1J(6) L1J(7)
    reduce4(a0, a1, a2, a3);
    const float hn = lstm_act4(a0, a1, a2, a3, bs, c);
    if (lane == 0) Hout[(size_t)(t + 1) * H + hid] = hn;
    grid_barrier<256>(bar, (unsigned)(t + 1), tid);
  }
}

// ===================== fused L2+L3+L4, named registers, role-pure blocks ====
#define L2XJ(j) { const float4 v = xr[(j)*64+lane]; \
  FMA4(i0##j,v,a0); FMA4(i1##j,v,a1); FMA4(i2##j,v,a2); FMA4(i3##j,v,a3); }
#define L2HJ(j) { const float4 v = hr[(j)*64+lane]; \
  FMA4(m0##j,v,a0); FMA4(m1##j,v,a1); FMA4(m2##j,v,a2); FMA4(m3##j,v,a3); }
#define L3XJ(j) { const float4 v = xr[(j)*64+lane]; \
  FMA4(d0##j,v,a0); FMA4(d1##j,v,a1); FMA4(d2##j,v,a2); FMA4(d3##j,v,a3); }
#define L3HJ(j) { const float4 v = hr[(j)*64+lane]; \
  FMA4(e0##j,v,a0); FMA4(e1##j,v,a1); FMA4(e2##j,v,a2); FMA4(e3##j,v,a3); }
#define L4XJ(j) { const float4 v = xr[(j)*64+lane]; \
  FMA4(f0##j,v,a0); FMA4(f1##j,v,a1); FMA4(f2##j,v,a2); FMA4(f3##j,v,a3); }

__global__ __launch_bounds__(512, 1)
void lstm_l234(const float* __restrict__ win2, const float* __restrict__ whh2,
               const float* __restrict__ bih2, const float* __restrict__ bhh2,
               const float* __restrict__ win3, const float* __restrict__ whh3,
               const float* __restrict__ bih3, const float* __restrict__ bhh3,
               const float* __restrict__ win4, const float* __restrict__ whh4,
               const float* __restrict__ bih4, const float* __restrict__ bhh4,
               const float* __restrict__ X2,   // = H1 + 2048 (row t = h1(t))
               float* __restrict__ H2t, float* __restrict__ H3t,
               float* __restrict__ H4t, float* __restrict__ out,
               unsigned* __restrict__ bar)
{
  const int tid = threadIdx.x, lane = tid & 63, wsl = tid >> 6;
  const int gw = blockIdx.x * 8 + wsl;        // 0..1791
  // role boundaries (1024, 1536) are multiples of 8 -> every block role-pure
  const int role = (blockIdx.x < 128) ? 0 : ((blockIdx.x < 192) ? 1 : 2);

  if (role == 0) {                            // L2: IN=2048 H=1024
    const int hid = gw;
    const size_t R0 = hid, R1 = 1024 + hid, R2 = 2048 + hid, R3 = 3072 + hid;
    const float4* pi0 = (const float4*)(win2 + R0 * 2048);
    const float4* pi1 = (const float4*)(win2 + R1 * 2048);
    const float4* pi2 = (const float4*)(win2 + R2 * 2048);
    const float4* pi3 = (const float4*)(win2 + R3 * 2048);
    const float4* ph0 = (const float4*)(whh2 + R0 * 1024);
    const float4* ph1 = (const float4*)(whh2 + R1 * 1024);
    const float4* ph2 = (const float4*)(whh2 + R2 * 1024);
    const float4* ph3 = (const float4*)(whh2 + R3 * 1024);
    float4 i00=pi0[0*64+lane], i01=pi0[1*64+lane], i02=pi0[2*64+lane], i03=pi0[3*64+lane],
           i04=pi0[4*64+lane], i05=pi0[5*64+lane], i06=pi0[6*64+lane], i07=pi0[7*64+lane];
    float4 i10=pi1[0*64+lane], i11=pi1[1*64+lane], i12=pi1[2*64+lane], i13=pi1[3*64+lane],
           i14=pi1[4*64+lane], i15=pi1[5*64+lane], i16=pi1[6*64+lane], i17=pi1[7*64+lane];
    float4 i20=pi2[0*64+lane], i21=pi2[1*64+lane], i22=pi2[2*64+lane], i23=pi2[3*64+lane],
           i24=pi2[4*64+lane], i25=pi2[5*64+lane], i26=pi2[6*64+lane], i27=pi2[7*64+lane];
    float4 i30=pi3[0*64+lane], i31=pi3[1*64+lane], i32=pi3[2*64+lane], i33=pi3[3*64+lane],
           i34=pi3[4*64+lane], i35=pi3[5*64+lane], i36=pi3[6*64+lane], i37=pi3[7*64+lane];
    float4 m00=ph0[0*64+lane], m01=ph0[1*64+lane], m02=ph0[2*64+lane], m03=ph0[3*64+lane];
    float4 m10=ph1[0*64+lane], m11=ph1[1*64+lane], m12=ph1[2*64+lane], m13=ph1[3*64+lane];
    float4 m20=ph2[0*64+lane], m21=ph2[1*64+lane], m22=ph2[2*64+lane], m23=ph2[3*64+lane];
    float4 m30=ph3[0*64+lane], m31=ph3[1*64+lane], m32=ph3[2*64+lane], m33=ph3[3*64+lane];
    PIN4(i00); PIN4(i01); PIN4(i02); PIN4(i03); PIN4(i04); PIN4(i05); PIN4(i06); PIN4(i07);
    PIN4(i10); PIN4(i11); PIN4(i12); PIN4(i13); PIN4(i14); PIN4(i15); PIN4(i16); PIN4(i17);
    PIN4(i20); PIN4(i21); PIN4(i22); PIN4(i23); PIN4(i24); PIN4(i25); PIN4(i26); PIN4(i27);
    PIN4(i30); PIN4(i31); PIN4(i32); PIN4(i33); PIN4(i34); PIN4(i35); PIN4(i36); PIN4(i37);
    PIN4(m00); PIN4(m01); PIN4(m02); PIN4(m03);
    PIN4(m10); PIN4(m11); PIN4(m12); PIN4(m13);
    PIN4(m20); PIN4(m21); PIN4(m22); PIN4(m23);
    PIN4(m30); PIN4(m31); PIN4(m32); PIN4(m33);
    float4 bs = make_float4(bih2[R0] + bhh2[R0], bih2[R1] + bhh2[R1],
                            bih2[R2] + bhh2[R2], bih2[R3] + bhh2[R3]);
    PIN4(bs);
    float c = 0.0f;
    #pragma unroll 1
    for (int s = 0; s < NSTEP + 2; ++s) {
      if (s < NSTEP) {
        const float4* xr = (const float4*)(X2  + (size_t)s * 2048);
        const float4* hr = (const float4*)(H2t + (size_t)s * 1024);
        float a0 = 0.f, a1 = 0.f, a2 = 0.f, a3 = 0.f;
        L2XJ(0) L2XJ(1) L2XJ(2) L2XJ(3) L2XJ(4) L2XJ(5) L2XJ(6) L2XJ(7)
        L2HJ(0) L2HJ(1) L2HJ(2) L2HJ(3)
        reduce4(a0, a1, a2, a3);
        const float hn = lstm_act4(a0, a1, a2, a3, bs, c);
        if (lane == 0) H2t[(size_t)(s + 1) * 1024 + hid] = hn;
      }
      grid_barrier<224>(bar, (unsigned)(s + 1), tid);
    }
  } else if (role == 1) {                     // L3: IN=1024 H=512
    const int hid = gw - 1024;
    const float* X3 = H2t + 1024;             // row t = h2(t)
    const size_t R0 = hid, R1 = 512 + hid, R2 = 1024 + hid, R3 = 1536 + hid;
    const float4* pi0 = (const float4*)(win3 + R0 * 1024);
    const float4* pi1 = (const float4*)(win3 + R1 * 1024);
    const float4* pi2 = (const float4*)(win3 + R2 * 1024);
    const float4* pi3 = (const float4*)(win3 + R3 * 1024);
    const float4* ph0 = (const float4*)(whh3 + R0 * 512);
    const float4* ph1 = (const float4*)(whh3 + R1 * 512);
    const float4* ph2 = (const float4*)(whh3 + R2 * 512);
    const float4* ph3 = (const float4*)(whh3 + R3 * 512);
    float4 d00=pi0[0*64+lane], d01=pi0[1*64+lane], d02=pi0[2*64+lane], d03=pi0[3*64+lane];
    float4 d10=pi1[0*64+lane], d11=pi1[1*64+lane], d12=pi1[2*64+lane], d13=pi1[3*64+lane];
    float4 d20=pi2[0*64+lane], d21=pi2[1*64+lane], d22=pi2[2*64+lane], d23=pi2[3*64+lane];
    float4 d30=pi3[0*64+lane], d31=pi3[1*64+lane], d32=pi3[2*64+lane], d33=pi3[3*64+lane];
    float4 e00=ph0[0*64+lane], e01=ph0[1*64+lane];
    float4 e10=ph1[0*64+lane], e11=ph1[1*64+lane];
    float4 e20=ph2[0*64+lane], e21=ph2[1*64+lane];
    float4 e30=ph3[0*64+lane], e31=ph3[1*64+lane];
    PIN4(d00); PIN4(d01); PIN4(d02); PIN4(d03);
    PIN4(d10); PIN4(d11); PIN4(d12); PIN4(d13);
    PIN4(d20); PIN4(d21); PIN4(d22); PIN4(d23);
    PIN4(d30); PIN4(d31); PIN4(d32); PIN4(d33);
    PIN4(e00); PIN4(e01); PIN4(e10); PIN4(e11);
    PIN4(e20); PIN4(e21); PIN4(e30); PIN4(e31);
    float4 bs = make_float4(bih3[R0] + bhh3[R0], bih3[R1] + bhh3[R1],
                            bih3[R2] + bhh3[R2], bih3[R3] + bhh3[R3]);
    PIN4(bs);
    float c = 0.0f;
    #pragma unroll 1
    for (int s = 0; s < NSTEP + 2; ++s) {
      if (s >= 1 && s <= NSTEP) {
        const int t3 = s - 1;
        const float4* xr = (const float4*)(X3  + (size_t)t3 * 1024);
        const float4* hr = (const float4*)(H3t + (size_t)t3 * 512);
        float a0 = 0.f, a1 = 0.f, a2 = 0.f, a3 = 0.f;
        L3XJ(0) L3XJ(1) L3XJ(2) L3XJ(3)
        L3HJ(0) L3HJ(1)
        reduce4(a0, a1, a2, a3);
        const float hn = lstm_act4(a0, a1, a2, a3, bs, c);
        if (lane == 0) H3t[(size_t)(t3 + 1) * 512 + hid] = hn;
      }
      grid_barrier<224>(bar, (unsigned)(s + 1), tid);
    }
  } else {                                    // L4: IN=512 H=256
    const int hid = gw - 1536;
    const float* X4 = H3t + 512;              // row t = h3(t)
    const size_t R0 = hid, R1 = 256 + hid, R2 = 512 + hid, R3 = 768 + hid;
    const float4* pi0 = (const float4*)(win4 + R0 * 512);
    const float4* pi1 = (const float4*)(win4 + R1 * 512);
    const float4* pi2 = (const float4*)(win4 + R2 * 512);
    const float4* pi3 = (const float4*)(win4 + R3 * 512);
    const float4* ph0 = (const float4*)(whh4 + R0 * 256);
    const float4* ph1 = (const float4*)(whh4 + R1 * 256);
    const float4* ph2 = (const float4*)(whh4 + R2 * 256);
    const float4* ph3 = (const float4*)(whh4 + R3 * 256);
    float4 f00=pi0[0*64+lane], f01=pi0[1*64+lane];
    float4 f10=pi1[0*64+lane], f11=pi1[1*64+lane];
    float4 f20=pi2[0*64+lane], f21=pi2[1*64+lane];
    float4 f30=pi3[0*64+lane], f31=pi3[1*64+lane];
    float4 g0=ph0[lane], g1=ph1[lane], g2=ph2[lane], g3=ph3[lane];
    PIN4(f00); PIN4(f01); PIN4(f10); PIN4(f11);
    PIN4(f20); PIN4(f21); PIN4(f30); PIN4(f31);
    PIN4(g0); PIN4(g1); PIN4(g2); PIN4(g3);
    float4 bs = make_float4(bih4[R0] + bhh4[R0], bih4[R1] + bhh4[R1],
                            bih4[R2] + bhh4[R2], bih4[R3] + bhh4[R3]);
    PIN4(bs);
    float c = 0.0f;
    #pragma unroll 1
    for (int s = 0; s < NSTEP + 2; ++s) {
      if (s >= 2) {
        const int t4 = s - 2;
        const float4* xr = (const float4*)(X4  + (size_t)t4 * 512);
        const float4* hr = (const float4*)(H4t + (size_t)t4 * 256);
        float a0 = 0.f, a1 = 0.f, a2 = 0.f, a3 = 0.f;
        L4XJ(0) L4XJ(1)
        { const float4 v = hr[lane]; FMA4(g0,v,a0); FMA4(g1,v,a1); FMA4(g2,v,a2); FMA4(g3,v,a3); }
        reduce4(a0, a1, a2, a3);
        const float hn = lstm_act4(a0, a1, a2, a3, bs, c);
        if (lane == 0) {
          H4t[(size_t)(t4 + 1) * 256 + hid] = hn;
          out[(size_t)t4 * 256 + hid] = hn;
        }
      }
      grid_barrier<224>(bar, (unsigned)(s + 1), tid);
    }
  }
}

// ===================== Fallback: round-1 streaming path =====================
struct Params {
  const float* xn;
  const float* w_ih[4];
  const float* w_hh[4];
  const float* b_ih[4];
  const float* b_hh[4];
  float* h[4];
  float* c[4];
  float* out;
  int s;
};

__global__ __launch_bounds__(256) void step_kernel(Params p)
{
  const int lane = threadIdx.x & 63;
  const int W = blockIdx.x * 4 + (threadIdx.x >> 6);

  int layer, h, H, IN, t;
  if (W < 2048)      { layer = 0; h = W;        H = 2048; IN = 64;   t = p.s;     }
  else if (W < 3072) { layer = 1; h = W - 2048; H = 1024; IN = 2048; t = p.s - 1; }
  else if (W < 3584) { layer = 2; h = W - 3072; H = 512;  IN = 1024; t = p.s - 2; }
  else               { layer = 3; h = W - 3584; H = 256;  IN = 512;  t = p.s - 3; }
  if (t < 0 || t >= NSTEP) return;

  const float* xin;
  if (layer == 0) xin = p.xn + (size_t)t * 64;
  else            xin = p.h[layer - 1] + (size_t)(t & 1) * IN;
  const float* hprev = p.h[layer] + (size_t)((t + 1) & 1) * H;
  float*       hout  = p.h[layer] + (size_t)(t & 1) * H;
  const float* wih = p.w_ih[layer];
  const float* whh = p.w_hh[layer];

  float acc[4];
  #pragma unroll
  for (int g = 0; g < 4; ++g) {
    const size_t r = (size_t)g * H + h;
    const float* wi = wih + r * IN;
    const float* wh = whh + r * (size_t)H;
    float a = 0.0f;
    for (int k = lane; k < IN; k += 64) a += wi[k] * xin[k];
    for (int k = lane; k < H;  k += 64) a += wh[k] * hprev[k];
    acc[g] = a;
  }
  #pragma unroll
  for (int off = 32; off > 0; off >>= 1) {
    #pragma unroll
    for (int g = 0; g < 4; ++g) acc[g] += __shfl_down(acc[g], off);
  }
  if (lane == 0) {
    const float* bi = p.b_ih[layer];
    const float* bh = p.b_hh[layer];
    const float gi = acc[0] + bi[h]         + bh[h];
    const float gf = acc[1] + bi[H + h]     + bh[H + h];
    const float gg = acc[2] + bi[2 * H + h] + bh[2 * H + h];
    const float go = acc[3] + bi[3 * H + h] + bh[3 * H + h];
    const float ig = 1.0f / (1.0f + expf(-gi));
    const float fg = 1.0f / (1.0f + expf(-gf));
    const float og = 1.0f / (1.0f + expf(-go));
    const float gt = tanhf(gg);
    const float cn = fg * p.c[layer][h] + ig * gt;
    const float hn = og * tanhf(cn);
    p.c[layer][h] = cn;
    hout[h] = hn;
    if (layer == 3) p.out[(size_t)t * 256 + h] = hn;
  }
}

// ===================== host launch ==========================================
extern "C" void kernel_launch(void* const* d_in, const int* in_sizes, int n_in,
                              void* d_out, int out_size, void* d_ws, size_t ws_size,
                              hipStream_t stream)
{
  const float* x    = (const float*)d_in[0];
  const float* bn_w = (const float*)d_in[1];
  const float* bn_b = (const float*)d_in[2];
  const float* wih[4]; const float* whh[4]; const float* bih[4]; const float* bhh[4];
  for (int l = 0; l < 4; ++l) {
    wih[l] = (const float*)d_in[3 + 4 * l];
    whh[l] = (const float*)d_in[4 + 4 * l];
    bih[l] = (const float*)d_in[5 + 4 * l];
    bhh[l] = (const float*)d_in[6 + 4 * l];
  }
  float* out = (float*)d_out;

  const size_t XN  = (size_t)NSTEP * 64;
  const size_t NH1 = (size_t)(NSTEP + 1) * 2048;
  const size_t NH2 = (size_t)(NSTEP + 1) * 1024;
  const size_t NH3 = (size_t)(NSTEP + 1) * 512;
  const size_t NH4 = (size_t)(NSTEP + 1) * 256;
  const size_t need = 4096 + (XN + NH1 + NH2 + NH3 + NH4) * sizeof(float);

  if (ws_size >= need) {
    unsigned* bar = (unsigned*)d_ws;               // [0..255]=L1, [256..511]=fused
    float* fb = (float*)((char*)d_ws + 4096);
    float* xn = fb;
    float* H1 = xn + XN;
    float* H2 = H1 + NH1;
    float* H3 = H2 + NH2;
    float* H4 = H3 + NH3;

    hipMemsetAsync(bar, 0, 4096, stream);
    hipMemsetAsync(H1, 0, 2048 * sizeof(float), stream);
    hipMemsetAsync(H2, 0, 1024 * sizeof(float), stream);
    hipMemsetAsync(H3, 0,  512 * sizeof(float), stream);
    hipMemsetAsync(H4, 0,  256 * sizeof(float), stream);

    bn_kernel<<<1024, 256, 0, stream>>>(x, bn_w, bn_b, xn);

    lstm_l1<<<256, 512, 0, stream>>>(wih[0], whh[0], bih[0], bhh[0],
                                     xn, H1, bar);

    lstm_l234<<<224, 512, 0, stream>>>(wih[1], whh[1], bih[1], bhh[1],
                                       wih[2], whh[2], bih[2], bhh[2],
                                       wih[3], whh[3], bih[3], bhh[3],
                                       H1 + 2048, H2, H3, H4, out, bar + 256);
    return;
  }

  // -------- fallback: streaming pipeline (proven) --------
  Params p;
  for (int l = 0; l < 4; ++l) { p.w_ih[l] = wih[l]; p.w_hh[l] = whh[l];
                                p.b_ih[l] = bih[l]; p.b_hh[l] = bhh[l]; }
  float* ws = (float*)d_ws;
  float* xn = ws;
  float* st = ws + (size_t)NSTEP * 64;
  p.xn = xn;
  const int Hs[4] = {2048, 1024, 512, 256};
  float* cur = st;
  for (int l = 0; l < 4; ++l) { p.h[l] = cur; cur += 2 * Hs[l]; }
  for (int l = 0; l < 4; ++l) { p.c[l] = cur; cur += Hs[l]; }
  p.out = out;

  const size_t state_bytes = (size_t)(cur - st) * sizeof(float);
  hipMemsetAsync(st, 0, state_bytes, stream);
  bn_kernel<<<1024, 256, 0, stream>>>(x, bn_w, bn_b, xn);
  for (int s = 0; s < NSTEP + 3; ++s) {
    p.s = s;
    step_kernel<<<960, 256, 0, stream>>>(p);
  }
}

// Round 10
// 80624.725 us; speedup vs baseline: 1.0632x; 1.0632x over previous
//
#include <hip/hip_runtime.h>
#include <cstddef>

#define NSTEP 4096
// Pin a named float4 variable into VGPRs (unrematerializable asm-defined SSA).
#define PIN4(v) asm volatile("" : "+v"((v).x), "+v"((v).y), "+v"((v).z), "+v"((v).w))
#define FMA4(W,V,A) { (A)=fmaf((W).x,(V).x,(A)); (A)=fmaf((W).y,(V).y,(A)); (A)=fmaf((W).z,(V).z,(A)); (A)=fmaf((W).w,(V).w,(A)); }

// ===================== BatchNorm over timestep channels =====================
__global__ __launch_bounds__(256) void bn_kernel(const float* __restrict__ x,
                                                 const float* __restrict__ bn_w,
                                                 const float* __restrict__ bn_b,
                                                 float* __restrict__ xn)
{
  const int t   = blockIdx.x;        // 0..1023
  const int tid = threadIdx.x;       // 256 = B*F
  const int b   = tid >> 6;
  const int f   = tid & 63;
  const float v = x[((size_t)b * 1024 + t) * 64 + f];
  float s = v, ss = v * v;
  #pragma unroll
  for (int off = 32; off > 0; off >>= 1) {
    s  += __shfl_down(s, off);
    ss += __shfl_down(ss, off);
  }
  __shared__ float sh[8];
  const int w = tid >> 6;
  if ((tid & 63) == 0) { sh[w] = s; sh[4 + w] = ss; }
  __syncthreads();
  const float S    = sh[0] + sh[1] + sh[2] + sh[3];
  const float SS   = sh[4] + sh[5] + sh[6] + sh[7];
  const float mean = S * (1.0f / 256.0f);
  const float var  = SS * (1.0f / 256.0f) - mean * mean;  // biased, matches jnp.var
  const float inv  = rsqrtf(var + 1e-5f);
  const float scale = bn_w[t] * inv;
  const float shift = bn_b[t] - mean * scale;
  xn[((size_t)b * 1024 + t) * 64 + f] = v * scale + shift;
}

// ===================== grid barrier (proven rounds 4-9) =====================
template<int NBLK>
__device__ __forceinline__ void grid_barrier(unsigned* __restrict__ bar,
                                             unsigned step1, int tid)
{
  constexpr unsigned GSZ = NBLK / 8;
  __syncthreads();
  if (tid == 0) {
    unsigned* gcnt = bar + 16 + 16 * (blockIdx.x / GSZ);
    unsigned* root = bar;
    __builtin_amdgcn_fence(__ATOMIC_RELEASE, "agent");
    const unsigned a = __hip_atomic_fetch_add(gcnt, 1u, __ATOMIC_RELAXED,
                                              __HIP_MEMORY_SCOPE_AGENT);
    if (a == step1 * GSZ - 1u)
      __hip_atomic_fetch_add(root, 1u, __ATOMIC_RELAXED, __HIP_MEMORY_SCOPE_AGENT);
    const unsigned tgt = step1 * 8u;
    while (__hip_atomic_load(root, __ATOMIC_RELAXED, __HIP_MEMORY_SCOPE_AGENT) < tgt)
      __builtin_amdgcn_s_sleep(2);
    __builtin_amdgcn_fence(__ATOMIC_ACQUIRE, "agent");
  }
  __syncthreads();
}

// ===================== wave helpers =========================================
__device__ __forceinline__ void reduce4(float& a0, float& a1, float& a2, float& a3)
{
  #pragma unroll
  for (int off = 32; off; off >>= 1) {
    a0 += __shfl_xor(a0, off);
    a1 += __shfl_xor(a1, off);
    a2 += __shfl_xor(a2, off);
    a3 += __shfl_xor(a3, off);
  }
}

// bs = (b_i, b_f, b_g, b_o); a0..a3 = gate pre-activations (i,f,g,o)
__device__ __forceinline__ float lstm_act4(float a0, float a1, float a2, float a3,
                                           float4 bs, float& c)
{
  const float ig = 1.0f / (1.0f + expf(-(a0 + bs.x)));
  const float fg = 1.0f / (1.0f + expf(-(a1 + bs.y)));
  const float og = 1.0f / (1.0f + expf(-(a3 + bs.w)));
  const float gt = tanhf(a2 + bs.z);
  c = fg * c + ig * gt;
  return og * tanhf(c);
}

// ===================== Layer 1: weights in NAMED registers ==================
// amdgpu_waves_per_eu(2,2): pins the scheduler's occupancy TARGET at 2
// waves/EU (register budget 256/wave, no spill-to-gain-occupancy).
// __launch_bounds__ alone only sets the occupancy FLOOR; the RA was spilling
// ~120 regs/wave to chase ~6 waves/EU (rounds 6-9: VGPR_Count 84-128).
#define L1J(j) { const float4 v = hr[(j)*64 + lane]; \
  FMA4(h0##j, v, a0); FMA4(h1##j, v, a1); FMA4(h2##j, v, a2); FMA4(h3##j, v, a3); }

__global__ __launch_bounds__(512)
__attribute__((amdgpu_waves_per_eu(2, 2)))
void lstm_l1(const float* __restrict__ win, const float* __restrict__ whh,
             const float* __restrict__ bih, const float* __restrict__ bhh,
             const float* __restrict__ X,     // (4096,64) normalized input
             float* __restrict__ Hout,        // (4097,2048), row r = h(r-1)
             unsigned* __restrict__ bar)
{
  constexpr int H = 2048;
  const int tid = threadIdx.x, lane = tid & 63, wsl = tid >> 6;
  const int hid = blockIdx.x * 8 + wsl;       // 2048 waves == H

  const size_t r0 = (size_t)0 * H + hid, r1 = (size_t)1 * H + hid,
               r2 = (size_t)2 * H + hid, r3 = (size_t)3 * H + hid;
  float4 wi = make_float4(win[r0 * 64 + lane], win[r1 * 64 + lane],
                          win[r2 * 64 + lane], win[r3 * 64 + lane]);
  PIN4(wi);
  const float4* p0 = (const float4*)(whh + r0 * H);
  const float4* p1 = (const float4*)(whh + r1 * H);
  const float4* p2 = (const float4*)(whh + r2 * H);
  const float4* p3 = (const float4*)(whh + r3 * H);
  float4 h00=p0[0*64+lane], h01=p0[1*64+lane], h02=p0[2*64+lane], h03=p0[3*64+lane],
         h04=p0[4*64+lane], h05=p0[5*64+lane], h06=p0[6*64+lane], h07=p0[7*64+lane];
  float4 h10=p1[0*64+lane], h11=p1[1*64+lane], h12=p1[2*64+lane], h13=p1[3*64+lane],
         h14=p1[4*64+lane], h15=p1[5*64+lane], h16=p1[6*64+lane], h17=p1[7*64+lane];
  float4 h20=p2[0*64+lane], h21=p2[1*64+lane], h22=p2[2*64+lane], h23=p2[3*64+lane],
         h24=p2[4*64+lane], h25=p2[5*64+lane], h26=p2[6*64+lane], h27=p2[7*64+lane];
  float4 h30=p3[0*64+lane], h31=p3[1*64+lane], h32=p3[2*64+lane], h33=p3[3*64+lane],
         h34=p3[4*64+lane], h35=p3[5*64+lane], h36=p3[6*64+lane], h37=p3[7*64+lane];
  PIN4(h00); PIN4(h01); PIN4(h02); PIN4(h03); PIN4(h04); PIN4(h05); PIN4(h06); PIN4(h07);
  PIN4(h10); PIN4(h11); PIN4(h12); PIN4(h13); PIN4(h14); PIN4(h15); PIN4(h16); PIN4(h17);
  PIN4(h20); PIN4(h21); PIN4(h22); PIN4(h23); PIN4(h24); PIN4(h25); PIN4(h26); PIN4(h27);
  PIN4(h30); PIN4(h31); PIN4(h32); PIN4(h33); PIN4(h34); PIN4(h35); PIN4(h36); PIN4(h37);
  float4 bs = make_float4(bih[r0] + bhh[r0], bih[r1] + bhh[r1],
                          bih[r2] + bhh[r2], bih[r3] + bhh[r3]);
  PIN4(bs);
  float c = 0.0f;

  #pragma unroll 1
  for (int t = 0; t < NSTEP; ++t) {
    const float xv = X[(size_t)t * 64 + lane];
    const float4* hr = (const float4*)(Hout + (size_t)t * H);   // h(t-1)
    float a0 = wi.x * xv, a1 = wi.y * xv, a2 = wi.z * xv, a3 = wi.w * xv;
    L1J(0) L1J(1) L1J(2) L1J(3) L1J(4) L1J(5) L1J(6) L1J(7)
    reduce4(a0, a1, a2, a3);
    const float hn = lstm_act4(a0, a1, a2, a3, bs, c);
    if (lane == 0) Hout[(size_t)(t + 1) * H + hid] = hn;
    grid_barrier<256>(bar, (unsigned)(t + 1), tid);
  }
}

// ===================== fused L2+L3+L4, named registers, role-pure blocks ====
#define L2XJ(j) { const float4 v = xr[(j)*64+lane]; \
  FMA4(i0##j,v,a0); FMA4(i1##j,v,a1); FMA4(i2##j,v,a2); FMA4(i3##j,v,a3); }
#define L2HJ(j) { const float4 v = hr[(j)*64+lane]; \
  FMA4(m0##j,v,a0); FMA4(m1##j,v,a1); FMA4(m2##j,v,a2); FMA4(m3##j,v,a3); }
#define L3XJ(j) { const float4 v = xr[(j)*64+lane]; \
  FMA4(d0##j,v,a0); FMA4(d1##j,v,a1); FMA4(d2##j,v,a2); FMA4(d3##j,v,a3); }
#define L3HJ(j) { const float4 v = hr[(j)*64+lane]; \
  FMA4(e0##j,v,a0); FMA4(e1##j,v,a1); FMA4(e2##j,v,a2); FMA4(e3##j,v,a3); }
#define L4XJ(j) { const float4 v = xr[(j)*64+lane]; \
  FMA4(f0##j,v,a0); FMA4(f1##j,v,a1); FMA4(f2##j,v,a2); FMA4(f3##j,v,a3); }

__global__ __launch_bounds__(512)
__attribute__((amdgpu_waves_per_eu(2, 2)))
void lstm_l234(const float* __restrict__ win2, const float* __restrict__ whh2,
               const float* __restrict__ bih2, const float* __restrict__ bhh2,
               const float* __restrict__ win3, const float* __restrict__ whh3,
               const float* __restrict__ bih3, const float* __restrict__ bhh3,
               const float* __restrict__ win4, const float* __restrict__ whh4,
               const float* __restrict__ bih4, const float* __restrict__ bhh4,
               const float* __restrict__ X2,   // = H1 + 2048 (row t = h1(t))
               float* __restrict__ H2t, float* __restrict__ H3t,
               float* __restrict__ H4t, float* __restrict__ out,
               unsigned* __restrict__ bar)
{
  const int tid = threadIdx.x, lane = tid & 63, wsl = tid >> 6;
  const int gw = blockIdx.x * 8 + wsl;        // 0..1791
  // role boundaries (1024, 1536) are multiples of 8 -> every block role-pure
  const int role = (blockIdx.x < 128) ? 0 : ((blockIdx.x < 192) ? 1 : 2);

  if (role == 0) {                            // L2: IN=2048 H=1024
    const int hid = gw;
    const size_t R0 = hid, R1 = 1024 + hid, R2 = 2048 + hid, R3 = 3072 + hid;
    const float4* pi0 = (const float4*)(win2 + R0 * 2048);
    const float4* pi1 = (const float4*)(win2 + R1 * 2048);
    const float4* pi2 = (const float4*)(win2 + R2 * 2048);
    const float4* pi3 = (const float4*)(win2 + R3 * 2048);
    const float4* ph0 = (const float4*)(whh2 + R0 * 1024);
    const float4* ph1 = (const float4*)(whh2 + R1 * 1024);
    const float4* ph2 = (const float4*)(whh2 + R2 * 1024);
    const float4* ph3 = (const float4*)(whh2 + R3 * 1024);
    float4 i00=pi0[0*64+lane], i01=pi0[1*64+lane], i02=pi0[2*64+lane], i03=pi0[3*64+lane],
           i04=pi0[4*64+lane], i05=pi0[5*64+lane], i06=pi0[6*64+lane], i07=pi0[7*64+lane];
    float4 i10=pi1[0*64+lane], i11=pi1[1*64+lane], i12=pi1[2*64+lane], i13=pi1[3*64+lane],
           i14=pi1[4*64+lane], i15=pi1[5*64+lane], i16=pi1[6*64+lane], i17=pi1[7*64+lane];
    float4 i20=pi2[0*64+lane], i21=pi2[1*64+lane], i22=pi2[2*64+lane], i23=pi2[3*64+lane],
           i24=pi2[4*64+lane], i25=pi2[5*64+lane], i26=pi2[6*64+lane], i27=pi2[7*64+lane];
    float4 i30=pi3[0*64+lane], i31=pi3[1*64+lane], i32=pi3[2*64+lane], i33=pi3[3*64+lane],
           i34=pi3[4*64+lane], i35=pi3[5*64+lane], i36=pi3[6*64+lane], i37=pi3[7*64+lane];
    float4 m00=ph0[0*64+lane], m01=ph0[1*64+lane], m02=ph0[2*64+lane], m03=ph0[3*64+lane];
    float4 m10=ph1[0*64+lane], m11=ph1[1*64+lane], m12=ph1[2*64+lane], m13=ph1[3*64+lane];
    float4 m20=ph2[0*64+lane], m21=ph2[1*64+lane], m22=ph2[2*64+lane], m23=ph2[3*64+lane];
    float4 m30=ph3[0*64+lane], m31=ph3[1*64+lane], m32=ph3[2*64+lane], m33=ph3[3*64+lane];
    PIN4(i00); PIN4(i01); PIN4(i02); PIN4(i03); PIN4(i04); PIN4(i05); PIN4(i06); PIN4(i07);
    PIN4(i10); PIN4(i11); PIN4(i12); PIN4(i13); PIN4(i14); PIN4(i15); PIN4(i16); PIN4(i17);
    PIN4(i20); PIN4(i21); PIN4(i22); PIN4(i23); PIN4(i24); PIN4(i25); PIN4(i26); PIN4(i27);
    PIN4(i30); PIN4(i31); PIN4(i32); PIN4(i33); PIN4(i34); PIN4(i35); PIN4(i36); PIN4(i37);
    PIN4(m00); PIN4(m01); PIN4(m02); PIN4(m03);
    PIN4(m10); PIN4(m11); PIN4(m12); PIN4(m13);
    PIN4(m20); PIN4(m21); PIN4(m22); PIN4(m23);
    PIN4(m30); PIN4(m31); PIN4(m32); PIN4(m33);
    float4 bs = make_float4(bih2[R0] + bhh2[R0], bih2[R1] + bhh2[R1],
                            bih2[R2] + bhh2[R2], bih2[R3] + bhh2[R3]);
    PIN4(bs);
    float c = 0.0f;
    #pragma unroll 1
    for (int s = 0; s < NSTEP + 2; ++s) {
      if (s < NSTEP) {
        const float4* xr = (const float4*)(X2  + (size_t)s * 2048);
        const float4* hr = (const float4*)(H2t + (size_t)s * 1024);
        float a0 = 0.f, a1 = 0.f, a2 = 0.f, a3 = 0.f;
        L2XJ(0) L2XJ(1) L2XJ(2) L2XJ(3) L2XJ(4) L2XJ(5) L2XJ(6) L2XJ(7)
        L2HJ(0) L2HJ(1) L2HJ(2) L2HJ(3)
        reduce4(a0, a1, a2, a3);
        const float hn = lstm_act4(a0, a1, a2, a3, bs, c);
        if (lane == 0) H2t[(size_t)(s + 1) * 1024 + hid] = hn;
      }
      grid_barrier<224>(bar, (unsigned)(s + 1), tid);
    }
  } else if (role == 1) {                     // L3: IN=1024 H=512
    const int hid = gw - 1024;
    const float* X3 = H2t + 1024;             // row t = h2(t)
    const size_t R0 = hid, R1 = 512 + hid, R2 = 1024 + hid, R3 = 1536 + hid;
    const float4* pi0 = (const float4*)(win3 + R0 * 1024);
    const float4* pi1 = (const float4*)(win3 + R1 * 1024);
    const float4* pi2 = (const float4*)(win3 + R2 * 1024);
    const float4* pi3 = (const float4*)(win3 + R3 * 1024);
    const float4* ph0 = (const float4*)(whh3 + R0 * 512);
    const float4* ph1 = (const float4*)(whh3 + R1 * 512);
    const float4* ph2 = (const float4*)(whh3 + R2 * 512);
    const float4* ph3 = (const float4*)(whh3 + R3 * 512);
    float4 d00=pi0[0*64+lane], d01=pi0[1*64+lane], d02=pi0[2*64+lane], d03=pi0[3*64+lane];
    float4 d10=pi1[0*64+lane], d11=pi1[1*64+lane], d12=pi1[2*64+lane], d13=pi1[3*64+lane];
    float4 d20=pi2[0*64+lane], d21=pi2[1*64+lane], d22=pi2[2*64+lane], d23=pi2[3*64+lane];
    float4 d30=pi3[0*64+lane], d31=pi3[1*64+lane], d32=pi3[2*64+lane], d33=pi3[3*64+lane];
    float4 e00=ph0[0*64+lane], e01=ph0[1*64+lane];
    float4 e10=ph1[0*64+lane], e11=ph1[1*64+lane];
    float4 e20=ph2[0*64+lane], e21=ph2[1*64+lane];
    float4 e30=ph3[0*64+lane], e31=ph3[1*64+lane];
    PIN4(d00); PIN4(d01); PIN4(d02); PIN4(d03);
    PIN4(d10); PIN4(d11); PIN4(d12); PIN4(d13);
    PIN4(d20); PIN4(d21); PIN4(d22); PIN4(d23);
    PIN4(d30); PIN4(d31); PIN4(d32); PIN4(d33);
    PIN4(e00); PIN4(e01); PIN4(e10); PIN4(e11);
    PIN4(e20); PIN4(e21); PIN4(e30); PIN4(e31);
    float4 bs = make_float4(bih3[R0] + bhh3[R0], bih3[R1] + bhh3[R1],
                            bih3[R2] + bhh3[R2], bih3[R3] + bhh3[R3]);
    PIN4(bs);
    float c = 0.0f;
    #pragma unroll 1
    for (int s = 0; s < NSTEP + 2; ++s) {
      if (s >= 1 && s <= NSTEP) {
        const int t3 = s - 1;
        const float4* xr = (const float4*)(X3  + (size_t)t3 * 1024);
        const float4* hr = (const float4*)(H3t + (size_t)t3 * 512);
        float a0 = 0.f, a1 = 0.f, a2 = 0.f, a3 = 0.f;
        L3XJ(0) L3XJ(1) L3XJ(2) L3XJ(3)
        L3HJ(0) L3HJ(1)
        reduce4(a0, a1, a2, a3);
        const float hn = lstm_act4(a0, a1, a2, a3, bs, c);
        if (lane == 0) H3t[(size_t)(t3 + 1) * 512 + hid] = hn;
      }
      grid_barrier<224>(bar, (unsigned)(s + 1), tid);
    }
  } else {                                    // L4: IN=512 H=256
    const int hid = gw - 1536;
    const float* X4 = H3t + 512;              // row t = h3(t)
    const size_t R0 = hid, R1 = 256 + hid, R2 = 512 + hid, R3 = 768 + hid;
    const float4* pi0 = (const float4*)(win4 + R0 * 512);
    const float4* pi1 = (const float4*)(win4 + R1 * 512);
    const float4* pi2 = (const float4*)(win4 + R2 * 512);
    const float4* pi3 = (const float4*)(win4 + R3 * 512);
    const float4* ph0 = (const float4*)(whh4 + R0 * 256);
    const float4* ph1 = (const float4*)(whh4 + R1 * 256);
    const float4* ph2 = (const float4*)(whh4 + R2 * 256);
    const float4* ph3 = (const float4*)(whh4 + R3 * 256);
    float4 f00=pi0[0*64+lane], f01=pi0[1*64+lane];
    float4 f10=pi1[0*64+lane], f11=pi1[1*64+lane];
    float4 f20=pi2[0*64+lane], f21=pi2[1*64+lane];
    float4 f30=pi3[0*64+lane], f31=pi3[1*64+lane];
    float4 g0=ph0[lane], g1=ph1[lane], g2=ph2[lane], g3=ph3[lane];
    PIN4(f00); PIN4(f01); PIN4(f10); PIN4(f11);
    PIN4(f20); PIN4(f21); PIN4(f30); PIN4(f31);
    PIN4(g0); PIN4(g1); PIN4(g2); PIN4(g3);
    float4 bs = make_float4(bih4[R0] + bhh4[R0], bih4[R1] + bhh4[R1],
                            bih4[R2] + bhh4[R2], bih4[R3] + bhh4[R3]);
    PIN4(bs);
    float c = 0.0f;
    #pragma unroll 1
    for (int s = 0; s < NSTEP + 2; ++s) {
      if (s >= 2) {
        const int t4 = s - 2;
        const float4* xr = (const float4*)(X4  + (size_t)t4 * 512);
        const float4* hr = (const float4*)(H4t + (size_t)t4 * 256);
        float a0 = 0.f, a1 = 0.f, a2 = 0.f, a3 = 0.f;
        L4XJ(0) L4XJ(1)
        { const float4 v = hr[lane]; FMA4(g0,v,a0); FMA4(g1,v,a1); FMA4(g2,v,a2); FMA4(g3,v,a3); }
        reduce4(a0, a1, a2, a3);
        const float hn = lstm_act4(a0, a1, a2, a3, bs, c);
        if (lane == 0) {
          H4t[(size_t)(t4 + 1) * 256 + hid] = hn;
          out[(size_t)t4 * 256 + hid] = hn;
        }
      }
      grid_barrier<224>(bar, (unsigned)(s + 1), tid);
    }
  }
}

// ===================== Fallback: round-1 streaming path =====================
struct Params {
  const float* xn;
  const float* w_ih[4];
  const float* w_hh[4];
  const float* b_ih[4];
  const float* b_hh[4];
  float* h[4];
  float* c[4];
  float* out;
  int s;
};

__global__ __launch_bounds__(256) void step_kernel(Params p)
{
  const int lane = threadIdx.x & 63;
  const int W = blockIdx.x * 4 + (threadIdx.x >> 6);

  int layer, h, H, IN, t;
  if (W < 2048)      { layer = 0; h = W;        H = 2048; IN = 64;   t = p.s;     }
  else if (W < 3072) { layer = 1; h = W - 2048; H = 1024; IN = 2048; t = p.s - 1; }
  else if (W < 3584) { layer = 2; h = W - 3072; H = 512;  IN = 1024; t = p.s - 2; }
  else               { layer = 3; h = W - 3584; H = 256;  IN = 512;  t = p.s - 3; }
  if (t < 0 || t >= NSTEP) return;

  const float* xin;
  if (layer == 0) xin = p.xn + (size_t)t * 64;
  else            xin = p.h[layer - 1] + (size_t)(t & 1) * IN;
  const float* hprev = p.h[layer] + (size_t)((t + 1) & 1) * H;
  float*       hout  = p.h[layer] + (size_t)(t & 1) * H;
  const float* wih = p.w_ih[layer];
  const float* whh = p.w_hh[layer];

  float acc[4];
  #pragma unroll
  for (int g = 0; g < 4; ++g) {
    const size_t r = (size_t)g * H + h;
    const float* wi = wih + r * IN;
    const float* wh = whh + r * (size_t)H;
    float a = 0.0f;
    for (int k = lane; k < IN; k += 64) a += wi[k] * xin[k];
    for (int k = lane; k < H;  k += 64) a += wh[k] * hprev[k];
    acc[g] = a;
  }
  #pragma unroll
  for (int off = 32; off > 0; off >>= 1) {
    #pragma unroll
    for (int g = 0; g < 4; ++g) acc[g] += __shfl_down(acc[g], off);
  }
  if (lane == 0) {
    const float* bi = p.b_ih[layer];
    const float* bh = p.b_hh[layer];
    const float gi = acc[0] + bi[h]         + bh[h];
    const float gf = acc[1] + bi[H + h]     + bh[H + h];
    const float gg = acc[2] + bi[2 * H + h] + bh[2 * H + h];
    const float go = acc[3] + bi[3 * H + h] + bh[3 * H + h];
    const float ig = 1.0f / (1.0f + expf(-gi));
    const float fg = 1.0f / (1.0f + expf(-gf));
    const float og = 1.0f / (1.0f + expf(-go));
    const float gt = tanhf(gg);
    const float cn = fg * p.c[layer][h] + ig * gt;
    const float hn = og * tanhf(cn);
    p.c[layer][h] = cn;
    hout[h] = hn;
    if (layer == 3) p.out[(size_t)t * 256 + h] = hn;
  }
}

// ===================== host launch ==========================================
extern "C" void kernel_launch(void* const* d_in, const int* in_sizes, int n_in,
                              void* d_out, int out_size, void* d_ws, size_t ws_size,
                              hipStream_t stream)
{
  const float* x    = (const float*)d_in[0];
  const float* bn_w = (const float*)d_in[1];
  const float* bn_b = (const float*)d_in[2];
  const float* wih[4]; const float* whh[4]; const float* bih[4]; const float* bhh[4];
  for (int l = 0; l < 4; ++l) {
    wih[l] = (const float*)d_in[3 + 4 * l];
    whh[l] = (const float*)d_in[4 + 4 * l];
    bih[l] = (const float*)d_in[5 + 4 * l];
    bhh[l] = (const float*)d_in[6 + 4 * l];
  }
  float* out = (float*)d_out;

  const size_t XN  = (size_t)NSTEP * 64;
  const size_t NH1 = (size_t)(NSTEP + 1) * 2048;
  const size_t NH2 = (size_t)(NSTEP + 1) * 1024;
  const size_t NH3 = (size_t)(NSTEP + 1) * 512;
  const size_t NH4 = (size_t)(NSTEP + 1) * 256;
  const size_t need = 4096 + (XN + NH1 + NH2 + NH3 + NH4) * sizeof(float);

  if (ws_size >= need) {
    unsigned* bar = (unsigned*)d_ws;               // [0..255]=L1, [256..511]=fused
    float* fb = (float*)((char*)d_ws + 4096);
    float* xn = fb;
    float* H1 = xn + XN;
    float* H2 = H1 + NH1;
    float* H3 = H2 + NH2;
    float* H4 = H3 + NH3;

    hipMemsetAsync(bar, 0, 4096, stream);
    hipMemsetAsync(H1, 0, 2048 * sizeof(float), stream);
    hipMemsetAsync(H2, 0, 1024 * sizeof(float), stream);
    hipMemsetAsync(H3, 0,  512 * sizeof(float), stream);
    hipMemsetAsync(H4, 0,  256 * sizeof(float), stream);

    bn_kernel<<<1024, 256, 0, stream>>>(x, bn_w, bn_b, xn);

    lstm_l1<<<256, 512, 0, stream>>>(wih[0], whh[0], bih[0], bhh[0],
                                     xn, H1, bar);

    lstm_l234<<<224, 512, 0, stream>>>(wih[1], whh[1], bih[1], bhh[1],
                                       wih[2], whh[2], bih[2], bhh[2],
                                       wih[3], whh[3], bih[3], bhh[3],
                                       H1 + 2048, H2, H3, H4, out, bar + 256);
    return;
  }

  // -------- fallback: streaming pipeline (proven) --------
  Params p;
  for (int l = 0; l < 4; ++l) { p.w_ih[l] = wih[l]; p.w_hh[l] = whh[l];
                                p.b_ih[l] = bih[l]; p.b_hh[l] = bhh[l]; }
  float* ws = (float*)d_ws;
  float* xn = ws;
  float* st = ws + (size_t)NSTEP * 64;
  p.xn = xn;
  const int Hs[4] = {2048, 1024, 512, 256};
  float* cur = st;
  for (int l = 0; l < 4; ++l) { p.h[l] = cur; cur += 2 * Hs[l]; }
  for (int l = 0; l < 4; ++l) { p.c[l] = cur; cur += Hs[l]; }
  p.out = out;

  const size_t state_bytes = (size_t)(cur - st) * sizeof(float);
  hipMemsetAsync(st, 0, state_bytes, stream);
  bn_kernel<<<1024, 256, 0, stream>>>(x, bn_w, bn_b, xn);
  for (int s = 0; s < NSTEP + 3; ++s) {
    p.s = s;
    step_kernel<<<960, 256, 0, stream>>>(p);
  }
}

// Round 11
// 53480.823 us; speedup vs baseline: 1.6029x; 1.5075x over previous
//
#include <hip/hip_runtime.h>
#include <cstddef>

#define NSTEP 4096
// Pin a named float4 variable into VGPRs (unrematerializable asm-defined SSA).
#define PIN4(v) asm volatile("" : "+v"((v).x), "+v"((v).y), "+v"((v).z), "+v"((v).w))
#define FMA4(W,V,A) { (A)=fmaf((W).x,(V).x,(A)); (A)=fmaf((W).y,(V).y,(A)); (A)=fmaf((W).z,(V).z,(A)); (A)=fmaf((W).w,(V).w,(A)); }

// Device-scope (cross-XCD) coherent scalar load/store: relaxed atomics compile
// to sc1 memory ops that go to the LLC without fencing/invalidating any L2.
__device__ __forceinline__ float ldc(const float* p) {
  return __hip_atomic_load(p, __ATOMIC_RELAXED, __HIP_MEMORY_SCOPE_AGENT);
}
__device__ __forceinline__ void stc(float* p, float v) {
  __hip_atomic_store(p, v, __ATOMIC_RELAXED, __HIP_MEMORY_SCOPE_AGENT);
}

// ===================== BatchNorm over timestep channels =====================
__global__ __launch_bounds__(256) void bn_kernel(const float* __restrict__ x,
                                                 const float* __restrict__ bn_w,
                                                 const float* __restrict__ bn_b,
                                                 float* __restrict__ xn)
{
  const int t   = blockIdx.x;        // 0..1023
  const int tid = threadIdx.x;       // 256 = B*F
  const int b   = tid >> 6;
  const int f   = tid & 63;
  const float v = x[((size_t)b * 1024 + t) * 64 + f];
  float s = v, ss = v * v;
  #pragma unroll
  for (int off = 32; off > 0; off >>= 1) {
    s  += __shfl_down(s, off);
    ss += __shfl_down(ss, off);
  }
  __shared__ float sh[8];
  const int w = tid >> 6;
  if ((tid & 63) == 0) { sh[w] = s; sh[4 + w] = ss; }
  __syncthreads();
  const float S    = sh[0] + sh[1] + sh[2] + sh[3];
  const float SS   = sh[4] + sh[5] + sh[6] + sh[7];
  const float mean = S * (1.0f / 256.0f);
  const float var  = SS * (1.0f / 256.0f) - mean * mean;  // biased, matches jnp.var
  const float inv  = rsqrtf(var + 1e-5f);
  const float scale = bn_w[t] * inv;
  const float shift = bn_b[t] - mean * scale;
  xn[((size_t)b * 1024 + t) * 64 + f] = v * scale + shift;
}

// ===================== FENCE-FREE grid barrier ==============================
// No agent fences (those compile to per-step L2 writeback/invalidate on
// non-coherent XCD L2s -- the round-10 10us/step killer). Ordering:
//  - producers store h via sc1 (LLC write-through) + s_waitcnt vmcnt(0)
//  - __syncthreads() before tid0's RMW -> all waves' stores at LLC
//  - counters are agent-scope RMWs/loads (execute at LLC)
//  - "memory" clobber stops compiler hoisting reads above the poll; sc1 reads
//    issued after the poll observe LLC state (LLC is the serialization point)
template<int NBLK>
__device__ __forceinline__ void grid_barrier(unsigned* __restrict__ bar,
                                             unsigned step1, int tid)
{
  constexpr unsigned GSZ = NBLK / 8;
  __syncthreads();
  if (tid == 0) {
    unsigned* gcnt = bar + 16 + 16 * (blockIdx.x / GSZ);
    unsigned* root = bar;
    const unsigned a = __hip_atomic_fetch_add(gcnt, 1u, __ATOMIC_RELAXED,
                                              __HIP_MEMORY_SCOPE_AGENT);
    if (a == step1 * GSZ - 1u)
      __hip_atomic_fetch_add(root, 1u, __ATOMIC_RELAXED, __HIP_MEMORY_SCOPE_AGENT);
    const unsigned tgt = step1 * 8u;
    while (__hip_atomic_load(root, __ATOMIC_RELAXED, __HIP_MEMORY_SCOPE_AGENT) < tgt)
      __builtin_amdgcn_s_sleep(2);
    asm volatile("" ::: "memory");
  }
  __syncthreads();
}

// ===================== wave helpers =========================================
__device__ __forceinline__ void reduce4(float& a0, float& a1, float& a2, float& a3)
{
  #pragma unroll
  for (int off = 32; off; off >>= 1) {
    a0 += __shfl_xor(a0, off);
    a1 += __shfl_xor(a1, off);
    a2 += __shfl_xor(a2, off);
    a3 += __shfl_xor(a3, off);
  }
}

// bs = (b_i, b_f, b_g, b_o); a0..a3 = gate pre-activations (i,f,g,o)
__device__ __forceinline__ float lstm_act4(float a0, float a1, float a2, float a3,
                                           float4 bs, float& c)
{
  const float ig = 1.0f / (1.0f + expf(-(a0 + bs.x)));
  const float fg = 1.0f / (1.0f + expf(-(a1 + bs.y)));
  const float og = 1.0f / (1.0f + expf(-(a3 + bs.w)));
  const float gt = tanhf(a2 + bs.z);
  c = fg * c + ig * gt;
  return og * tanhf(c);
}

// ===================== Layer 1 ==============================================
// Weights in named-PIN registers (or warm-L2 spill slots -- now cheap, since
// no per-step L2 invalidation). Shared h(t-1) row staged once per block into
// LDS via sc1 loads; FMA loop reads LDS. Same float values, same FMA order.
#define L1J(j) { const float4 v = *(const float4*)&hbuf[(j)*256 + lane*4]; \
  FMA4(h0##j, v, a0); FMA4(h1##j, v, a1); FMA4(h2##j, v, a2); FMA4(h3##j, v, a3); }

__global__ __launch_bounds__(512)
__attribute__((amdgpu_waves_per_eu(2, 2)))
void lstm_l1(const float* __restrict__ win, const float* __restrict__ whh,
             const float* __restrict__ bih, const float* __restrict__ bhh,
             const float* __restrict__ X,     // (4096,64) normalized input
             float* __restrict__ Hout,        // (4097,2048), row r = h(r-1)
             unsigned* __restrict__ bar)
{
  constexpr int H = 2048;
  __shared__ __align__(16) float hbuf[2048];
  const int tid = threadIdx.x, lane = tid & 63, wsl = tid >> 6;
  const int hid = blockIdx.x * 8 + wsl;       // 2048 waves == H

  const size_t r0 = (size_t)0 * H + hid, r1 = (size_t)1 * H + hid,
               r2 = (size_t)2 * H + hid, r3 = (size_t)3 * H + hid;
  float4 wi = make_float4(win[r0 * 64 + lane], win[r1 * 64 + lane],
                          win[r2 * 64 + lane], win[r3 * 64 + lane]);
  PIN4(wi);
  const float4* p0 = (const float4*)(whh + r0 * H);
  const float4* p1 = (const float4*)(whh + r1 * H);
  const float4* p2 = (const float4*)(whh + r2 * H);
  const float4* p3 = (const float4*)(whh + r3 * H);
  float4 h00=p0[0*64+lane], h01=p0[1*64+lane], h02=p0[2*64+lane], h03=p0[3*64+lane],
         h04=p0[4*64+lane], h05=p0[5*64+lane], h06=p0[6*64+lane], h07=p0[7*64+lane];
  float4 h10=p1[0*64+lane], h11=p1[1*64+lane], h12=p1[2*64+lane], h13=p1[3*64+lane],
         h14=p1[4*64+lane], h15=p1[5*64+lane], h16=p1[6*64+lane], h17=p1[7*64+lane];
  float4 h20=p2[0*64+lane], h21=p2[1*64+lane], h22=p2[2*64+lane], h23=p2[3*64+lane],
         h24=p2[4*64+lane], h25=p2[5*64+lane], h26=p2[6*64+lane], h27=p2[7*64+lane];
  float4 h30=p3[0*64+lane], h31=p3[1*64+lane], h32=p3[2*64+lane], h33=p3[3*64+lane],
         h34=p3[4*64+lane], h35=p3[5*64+lane], h36=p3[6*64+lane], h37=p3[7*64+lane];
  PIN4(h00); PIN4(h01); PIN4(h02); PIN4(h03); PIN4(h04); PIN4(h05); PIN4(h06); PIN4(h07);
  PIN4(h10); PIN4(h11); PIN4(h12); PIN4(h13); PIN4(h14); PIN4(h15); PIN4(h16); PIN4(h17);
  PIN4(h20); PIN4(h21); PIN4(h22); PIN4(h23); PIN4(h24); PIN4(h25); PIN4(h26); PIN4(h27);
  PIN4(h30); PIN4(h31); PIN4(h32); PIN4(h33); PIN4(h34); PIN4(h35); PIN4(h36); PIN4(h37);
  float4 bs = make_float4(bih[r0] + bhh[r0], bih[r1] + bhh[r1],
                          bih[r2] + bhh[r2], bih[r3] + bhh[r3]);
  PIN4(bs);
  float c = 0.0f;

  #pragma unroll 1
  for (int t = 0; t < NSTEP; ++t) {
    // stage h(t-1) row (coherent sc1 reads -> LDS), shared by the 8 waves
    {
      const float* hrow = Hout + (size_t)t * H;
      #pragma unroll
      for (int k = 0; k < 4; ++k) hbuf[tid + 512 * k] = ldc(hrow + tid + 512 * k);
    }
    __syncthreads();
    const float xv = X[(size_t)t * 64 + lane];       // prior-kernel data: plain
    float a0 = wi.x * xv, a1 = wi.y * xv, a2 = wi.z * xv, a3 = wi.w * xv;
    L1J(0) L1J(1) L1J(2) L1J(3) L1J(4) L1J(5) L1J(6) L1J(7)
    reduce4(a0, a1, a2, a3);
    const float hn = lstm_act4(a0, a1, a2, a3, bs, c);
    if (lane == 0) stc(&Hout[(size_t)(t + 1) * H + hid], hn);
    asm volatile("s_waitcnt vmcnt(0)" ::: "memory");   // h at LLC before count
    grid_barrier<256>(bar, (unsigned)(t + 1), tid);
  }
}

// ===================== fused L2+L3+L4, role-pure blocks =====================
#define L2XJ(j) { const float4 v = xr[(j)*64+lane]; \
  FMA4(i0##j,v,a0); FMA4(i1##j,v,a1); FMA4(i2##j,v,a2); FMA4(i3##j,v,a3); }
#define L2HJ(j) { const float4 v = *(const float4*)&hbuf[(j)*256+lane*4]; \
  FMA4(m0##j,v,a0); FMA4(m1##j,v,a1); FMA4(m2##j,v,a2); FMA4(m3##j,v,a3); }
#define L3XJ(j) { const float4 v = *(const float4*)&hbuf[(j)*256+lane*4]; \
  FMA4(d0##j,v,a0); FMA4(d1##j,v,a1); FMA4(d2##j,v,a2); FMA4(d3##j,v,a3); }
#define L3HJ(j) { const float4 v = *(const float4*)&hbuf[4096 + (j)*256+lane*4]; \
  FMA4(e0##j,v,a0); FMA4(e1##j,v,a1); FMA4(e2##j,v,a2); FMA4(e3##j,v,a3); }
#define L4XJ(j) { const float4 v = *(const float4*)&hbuf[(j)*256+lane*4]; \
  FMA4(f0##j,v,a0); FMA4(f1##j,v,a1); FMA4(f2##j,v,a2); FMA4(f3##j,v,a3); }

__global__ __launch_bounds__(512)
__attribute__((amdgpu_waves_per_eu(2, 2)))
void lstm_l234(const float* __restrict__ win2, const float* __restrict__ whh2,
               const float* __restrict__ bih2, const float* __restrict__ bhh2,
               const float* __restrict__ win3, const float* __restrict__ whh3,
               const float* __restrict__ bih3, const float* __restrict__ bhh3,
               const float* __restrict__ win4, const float* __restrict__ whh4,
               const float* __restrict__ bih4, const float* __restrict__ bhh4,
               const float* __restrict__ X2,   // = H1 + 2048 (row t = h1(t)), prior kernel
               float* __restrict__ H2t, float* __restrict__ H3t,
               float* __restrict__ H4t, float* __restrict__ out,
               unsigned* __restrict__ bar)
{
  __shared__ __align__(16) float hbuf[1536];   // max role need: L3 x(1024)+h(512)
  const int tid = threadIdx.x, lane = tid & 63, wsl = tid >> 6;
  const int gw = blockIdx.x * 8 + wsl;        // 0..1791
  const int role = (blockIdx.x < 128) ? 0 : ((blockIdx.x < 192) ? 1 : 2);
  // NOTE: L3HJ indexes hbuf at +4096 bytes? no -- floats; fix offset below.

  if (role == 0) {                            // L2: IN=2048 H=1024
    const int hid = gw;
    const size_t R0 = hid, R1 = 1024 + hid, R2 = 2048 + hid, R3 = 3072 + hid;
    const float4* pi0 = (const float4*)(win2 + R0 * 2048);
    const float4* pi1 = (const float4*)(win2 + R1 * 2048);
    const float4* pi2 = (const float4*)(win2 + R2 * 2048);
    const float4* pi3 = (const float4*)(win2 + R3 * 2048);
    const float4* ph0 = (const float4*)(whh2 + R0 * 1024);
    const float4* ph1 = (const float4*)(whh2 + R1 * 1024);
    const float4* ph2 = (const float4*)(whh2 + R2 * 1024);
    const float4* ph3 = (const float4*)(whh2 + R3 * 1024);
    float4 i00=pi0[0*64+lane], i01=pi0[1*64+lane], i02=pi0[2*64+lane], i03=pi0[3*64+lane],
           i04=pi0[4*64+lane], i05=pi0[5*64+lane], i06=pi0[6*64+lane], i07=pi0[7*64+lane];
    float4 i10=pi1[0*64+lane], i11=pi1[1*64+lane], i12=pi1[2*64+lane], i13=pi1[3*64+lane],
           i14=pi1[4*64+lane], i15=pi1[5*64+lane], i16=pi1[6*64+lane], i17=pi1[7*64+lane];
    float4 i20=pi2[0*64+lane], i21=pi2[1*64+lane], i22=pi2[2*64+lane], i23=pi2[3*64+lane],
           i24=pi2[4*64+lane], i25=pi2[5*64+lane], i26=pi2[6*64+lane], i27=pi2[7*64+lane];
    float4 i30=pi3[0*64+lane], i31=pi3[1*64+lane], i32=pi3[2*64+lane], i33=pi3[3*64+lane],
           i34=pi3[4*64+lane], i35=pi3[5*64+lane], i36=pi3[6*64+lane], i37=pi3[7*64+lane];
    float4 m00=ph0[0*64+lane], m01=ph0[1*64+lane], m02=ph0[2*64+lane], m03=ph0[3*64+lane];
    float4 m10=ph1[0*64+lane], m11=ph1[1*64+lane], m12=ph1[2*64+lane], m13=ph1[3*64+lane];
    float4 m20=ph2[0*64+lane], m21=ph2[1*64+lane], m22=ph2[2*64+lane], m23=ph2[3*64+lane];
    float4 m30=ph3[0*64+lane], m31=ph3[1*64+lane], m32=ph3[2*64+lane], m33=ph3[3*64+lane];
    PIN4(i00); PIN4(i01); PIN4(i02); PIN4(i03); PIN4(i04); PIN4(i05); PIN4(i06); PIN4(i07);
    PIN4(i10); PIN4(i11); PIN4(i12); PIN4(i13); PIN4(i14); PIN4(i15); PIN4(i16); PIN4(i17);
    PIN4(i20); PIN4(i21); PIN4(i22); PIN4(i23); PIN4(i24); PIN4(i25); PIN4(i26); PIN4(i27);
    PIN4(i30); PIN4(i31); PIN4(i32); PIN4(i33); PIN4(i34); PIN4(i35); PIN4(i36); PIN4(i37);
    PIN4(m00); PIN4(m01); PIN4(m02); PIN4(m03);
    PIN4(m10); PIN4(m11); PIN4(m12); PIN4(m13);
    PIN4(m20); PIN4(m21); PIN4(m22); PIN4(m23);
    PIN4(m30); PIN4(m31); PIN4(m32); PIN4(m33);
    float4 bs = make_float4(bih2[R0] + bhh2[R0], bih2[R1] + bhh2[R1],
                            bih2[R2] + bhh2[R2], bih2[R3] + bhh2[R3]);
    PIN4(bs);
    float c = 0.0f;
    #pragma unroll 1
    for (int s = 0; s < NSTEP + 2; ++s) {
      if (s < NSTEP) {
        {  // stage h2(s-1) row (in-kernel data -> coherent reads)
          const float* hrow = H2t + (size_t)s * 1024;
          #pragma unroll
          for (int k = 0; k < 2; ++k) hbuf[tid + 512 * k] = ldc(hrow + tid + 512 * k);
        }
        __syncthreads();
        const float4* xr = (const float4*)(X2 + (size_t)s * 2048);  // prior kernel: plain
        float a0 = 0.f, a1 = 0.f, a2 = 0.f, a3 = 0.f;
        L2XJ(0) L2XJ(1) L2XJ(2) L2XJ(3) L2XJ(4) L2XJ(5) L2XJ(6) L2XJ(7)
        L2HJ(0) L2HJ(1) L2HJ(2) L2HJ(3)
        reduce4(a0, a1, a2, a3);
        const float hn = lstm_act4(a0, a1, a2, a3, bs, c);
        if (lane == 0) stc(&H2t[(size_t)(s + 1) * 1024 + hid], hn);
        asm volatile("s_waitcnt vmcnt(0)" ::: "memory");
      }
      grid_barrier<224>(bar, (unsigned)(s + 1), tid);
    }
  } else if (role == 1) {                     // L3: IN=1024 H=512
    const int hid = gw - 1024;
    const float* X3 = H2t + 1024;             // row t = h2(t) (in-kernel!)
    const size_t R0 = hid, R1 = 512 + hid, R2 = 1024 + hid, R3 = 1536 + hid;
    const float4* pi0 = (const float4*)(win3 + R0 * 1024);
    const float4* pi1 = (const float4*)(win3 + R1 * 1024);
    const float4* pi2 = (const float4*)(win3 + R2 * 1024);
    const float4* pi3 = (const float4*)(win3 + R3 * 1024);
    const float4* ph0 = (const float4*)(whh3 + R0 * 512);
    const float4* ph1 = (const float4*)(whh3 + R1 * 512);
    const float4* ph2 = (const float4*)(whh3 + R2 * 512);
    const float4* ph3 = (const float4*)(whh3 + R3 * 512);
    float4 d00=pi0[0*64+lane], d01=pi0[1*64+lane], d02=pi0[2*64+lane], d03=pi0[3*64+lane];
    float4 d10=pi1[0*64+lane], d11=pi1[1*64+lane], d12=pi1[2*64+lane], d13=pi1[3*64+lane];
    float4 d20=pi2[0*64+lane], d21=pi2[1*64+lane], d22=pi2[2*64+lane], d23=pi2[3*64+lane];
    float4 d30=pi3[0*64+lane], d31=pi3[1*64+lane], d32=pi3[2*64+lane], d33=pi3[3*64+lane];
    float4 e00=ph0[0*64+lane], e01=ph0[1*64+lane];
    float4 e10=ph1[0*64+lane], e11=ph1[1*64+lane];
    float4 e20=ph2[0*64+lane], e21=ph2[1*64+lane];
    float4 e30=ph3[0*64+lane], e31=ph3[1*64+lane];
    PIN4(d00); PIN4(d01); PIN4(d02); PIN4(d03);
    PIN4(d10); PIN4(d11); PIN4(d12); PIN4(d13);
    PIN4(d20); PIN4(d21); PIN4(d22); PIN4(d23);
    PIN4(d30); PIN4(d31); PIN4(d32); PIN4(d33);
    PIN4(e00); PIN4(e01); PIN4(e10); PIN4(e11);
    PIN4(e20); PIN4(e21); PIN4(e30); PIN4(e31);
    float4 bs = make_float4(bih3[R0] + bhh3[R0], bih3[R1] + bhh3[R1],
                            bih3[R2] + bhh3[R2], bih3[R3] + bhh3[R3]);
    PIN4(bs);
    float c = 0.0f;
    #pragma unroll 1
    for (int s = 0; s < NSTEP + 2; ++s) {
      if (s >= 1 && s <= NSTEP) {
        const int t3 = s - 1;
        {  // stage x=h2(t3) (1024) and h3(t3-1) (512) -> LDS
          const float* xrow = X3  + (size_t)t3 * 1024;
          const float* hrow = H3t + (size_t)t3 * 512;
          #pragma unroll
          for (int k = 0; k < 2; ++k) hbuf[tid + 512 * k] = ldc(xrow + tid + 512 * k);
          hbuf[1024 + tid] = ldc(hrow + tid);
        }
        __syncthreads();
        float a0 = 0.f, a1 = 0.f, a2 = 0.f, a3 = 0.f;
        L3XJ(0) L3XJ(1) L3XJ(2) L3XJ(3)
        {
          const float4 v = *(const float4*)&hbuf[1024 + 0*256 + lane*4];
          FMA4(e00,v,a0); FMA4(e10,v,a1); FMA4(e20,v,a2); FMA4(e30,v,a3);
        }
        {
          const float4 v = *(const float4*)&hbuf[1024 + 1*256 + lane*4];
          FMA4(e01,v,a0); FMA4(e11,v,a1); FMA4(e21,v,a2); FMA4(e31,v,a3);
        }
        reduce4(a0, a1, a2, a3);
        const float hn = lstm_act4(a0, a1, a2, a3, bs, c);
        if (lane == 0) stc(&H3t[(size_t)(t3 + 1) * 512 + hid], hn);
        asm volatile("s_waitcnt vmcnt(0)" ::: "memory");
      }
      grid_barrier<224>(bar, (unsigned)(s + 1), tid);
    }
  } else {                                    // L4: IN=512 H=256
    const int hid = gw - 1536;
    const float* X4 = H3t + 512;              // row t = h3(t) (in-kernel!)
    const size_t R0 = hid, R1 = 256 + hid, R2 = 512 + hid, R3 = 768 + hid;
    const float4* pi0 = (const float4*)(win4 + R0 * 512);
    const float4* pi1 = (const float4*)(win4 + R1 * 512);
    const float4* pi2 = (const float4*)(win4 + R2 * 512);
    const float4* pi3 = (const float4*)(win4 + R3 * 512);
    const float4* ph0 = (const float4*)(whh4 + R0 * 256);
    const float4* ph1 = (const float4*)(whh4 + R1 * 256);
    const float4* ph2 = (const float4*)(whh4 + R2 * 256);
    const float4* ph3 = (const float4*)(whh4 + R3 * 256);
    float4 f00=pi0[0*64+lane], f01=pi0[1*64+lane];
    float4 f10=pi1[0*64+lane], f11=pi1[1*64+lane];
    float4 f20=pi2[0*64+lane], f21=pi2[1*64+lane];
    float4 f30=pi3[0*64+lane], f31=pi3[1*64+lane];
    float4 g0=ph0[lane], g1=ph1[lane], g2=ph2[lane], g3=ph3[lane];
    PIN4(f00); PIN4(f01); PIN4(f10); PIN4(f11);
    PIN4(f20); PIN4(f21); PIN4(f30); PIN4(f31);
    PIN4(g0); PIN4(g1); PIN4(g2); PIN4(g3);
    float4 bs = make_float4(bih4[R0] + bhh4[R0], bih4[R1] + bhh4[R1],
                            bih4[R2] + bhh4[R2], bih4[R3] + bhh4[R3]);
    PIN4(bs);
    float c = 0.0f;
    #pragma unroll 1
    for (int s = 0; s < NSTEP + 2; ++s) {
      if (s >= 2) {
        const int t4 = s - 2;
        {  // stage x=h3(t4) (512) and h4(t4-1) (256) -> LDS
          const float* xrow = X4  + (size_t)t4 * 512;
          const float* hrow = H4t + (size_t)t4 * 256;
          hbuf[tid] = ldc(xrow + tid);
          if (tid < 256) hbuf[512 + tid] = ldc(hrow + tid);
        }
        __syncthreads();
        float a0 = 0.f, a1 = 0.f, a2 = 0.f, a3 = 0.f;
        L4XJ(0) L4XJ(1)
        {
          const float4 v = *(const float4*)&hbuf[512 + lane*4];
          FMA4(g0,v,a0); FMA4(g1,v,a1); FMA4(g2,v,a2); FMA4(g3,v,a3);
        }
        reduce4(a0, a1, a2, a3);
        const float hn = lstm_act4(a0, a1, a2, a3, bs, c);
        if (lane == 0) {
          stc(&H4t[(size_t)(t4 + 1) * 256 + hid], hn);
          out[(size_t)t4 * 256 + hid] = hn;          // host-read: plain
        }
        asm volatile("s_waitcnt vmcnt(0)" ::: "memory");
      }
      grid_barrier<224>(bar, (unsigned)(s + 1), tid);
    }
  }
}

// ===================== Fallback: round-1 streaming path =====================
struct Params {
  const float* xn;
  const float* w_ih[4];
  const float* w_hh[4];
  const float* b_ih[4];
  const float* b_hh[4];
  float* h[4];
  float* c[4];
  float* out;
  int s;
};

__global__ __launch_bounds__(256) void step_kernel(Params p)
{
  const int lane = threadIdx.x & 63;
  const int W = blockIdx.x * 4 + (threadIdx.x >> 6);

  int layer, h, H, IN, t;
  if (W < 2048)      { layer = 0; h = W;        H = 2048; IN = 64;   t = p.s;     }
  else if (W < 3072) { layer = 1; h = W - 2048; H = 1024; IN = 2048; t = p.s - 1; }
  else if (W < 3584) { layer = 2; h = W - 3072; H = 512;  IN = 1024; t = p.s - 2; }
  else               { layer = 3; h = W - 3584; H = 256;  IN = 512;  t = p.s - 3; }
  if (t < 0 || t >= NSTEP) return;

  const float* xin;
  if (layer == 0) xin = p.xn + (size_t)t * 64;
  else            xin = p.h[layer - 1] + (size_t)(t & 1) * IN;
  const float* hprev = p.h[layer] + (size_t)((t + 1) & 1) * H;
  float*       hout  = p.h[layer] + (size_t)(t & 1) * H;
  const float* wih = p.w_ih[layer];
  const float* whh = p.w_hh[layer];

  float acc[4];
  #pragma unroll
  for (int g = 0; g < 4; ++g) {
    const size_t r = (size_t)g * H + h;
    const float* wi = wih + r * IN;
    const float* wh = whh + r * (size_t)H;
    float a = 0.0f;
    for (int k = lane; k < IN; k += 64) a += wi[k] * xin[k];
    for (int k = lane; k < H;  k += 64) a += wh[k] * hprev[k];
    acc[g] = a;
  }
  #pragma unroll
  for (int off = 32; off > 0; off >>= 1) {
    #pragma unroll
    for (int g = 0; g < 4; ++g) acc[g] += __shfl_down(acc[g], off);
  }
  if (lane == 0) {
    const float* bi = p.b_ih[layer];
    const float* bh = p.b_hh[layer];
    const float gi = acc[0] + bi[h]         + bh[h];
    const float gf = acc[1] + bi[H + h]     + bh[H + h];
    const float gg = acc[2] + bi[2 * H + h] + bh[2 * H + h];
    const float go = acc[3] + bi[3 * H + h] + bh[3 * H + h];
    const float ig = 1.0f / (1.0f + expf(-gi));
    const float fg = 1.0f / (1.0f + expf(-gf));
    const float og = 1.0f / (1.0f + expf(-go));
    const float gt = tanhf(gg);
    const float cn = fg * p.c[layer][h] + ig * gt;
    const float hn = og * tanhf(cn);
    p.c[layer][h] = cn;
    hout[h] = hn;
    if (layer == 3) p.out[(size_t)t * 256 + h] = hn;
  }
}

// ===================== host launch ==========================================
extern "C" void kernel_launch(void* const* d_in, const int* in_sizes, int n_in,
                              void* d_out, int out_size, void* d_ws, size_t ws_size,
                              hipStream_t stream)
{
  const float* x    = (const float*)d_in[0];
  const float* bn_w = (const float*)d_in[1];
  const float* bn_b = (const float*)d_in[2];
  const float* wih[4]; const float* whh[4]; const float* bih[4]; const float* bhh[4];
  for (int l = 0; l < 4; ++l) {
    wih[l] = (const float*)d_in[3 + 4 * l];
    whh[l] = (const float*)d_in[4 + 4 * l];
    bih[l] = (const float*)d_in[5 + 4 * l];
    bhh[l] = (const float*)d_in[6 + 4 * l];
  }
  float* out = (float*)d_out;

  const size_t XN  = (size_t)NSTEP * 64;
  const size_t NH1 = (size_t)(NSTEP + 1) * 2048;
  const size_t NH2 = (size_t)(NSTEP + 1) * 1024;
  const size_t NH3 = (size_t)(NSTEP + 1) * 512;
  const size_t NH4 = (size_t)(NSTEP + 1) * 256;
  const size_t need = 4096 + (XN + NH1 + NH2 + NH3 + NH4) * sizeof(float);

  if (ws_size >= need) {
    unsigned* bar = (unsigned*)d_ws;               // [0..255]=L1, [256..511]=fused
    float* fb = (float*)((char*)d_ws + 4096);
    float* xn = fb;
    float* H1 = xn + XN;
    float* H2 = H1 + NH1;
    float* H3 = H2 + NH2;
    float* H4 = H3 + NH3;

    hipMemsetAsync(bar, 0, 4096, stream);
    hipMemsetAsync(H1, 0, 2048 * sizeof(float), stream);
    hipMemsetAsync(H2, 0, 1024 * sizeof(float), stream);
    hipMemsetAsync(H3, 0,  512 * sizeof(float), stream);
    hipMemsetAsync(H4, 0,  256 * sizeof(float), stream);

    bn_kernel<<<1024, 256, 0, stream>>>(x, bn_w, bn_b, xn);

    lstm_l1<<<256, 512, 0, stream>>>(wih[0], whh[0], bih[0], bhh[0],
                                     xn, H1, bar);

    lstm_l234<<<224, 512, 0, stream>>>(wih[1], whh[1], bih[1], bhh[1],
                                       wih[2], whh[2], bih[2], bhh[2],
                                       wih[3], whh[3], bih[3], bhh[3],
                                       H1 + 2048, H2, H3, H4, out, bar + 256);
    return;
  }

  // -------- fallback: streaming pipeline (proven) --------
  Params p;
  for (int l = 0; l < 4; ++l) { p.w_ih[l] = wih[l]; p.w_hh[l] = whh[l];
                                p.b_ih[l] = bih[l]; p.b_hh[l] = bhh[l]; }
  float* ws = (float*)d_ws;
  float* xn = ws;
  float* st = ws + (size_t)NSTEP * 64;
  p.xn = xn;
  const int Hs[4] = {2048, 1024, 512, 256};
  float* cur = st;
  for (int l = 0; l < 4; ++l) { p.h[l] = cur; cur += 2 * Hs[l]; }
  for (int l = 0; l < 4; ++l) { p.c[l] = cur; cur += Hs[l]; }
  p.out = out;

  const size_t state_bytes = (size_t)(cur - st) * sizeof(float);
  hipMemsetAsync(st, 0, state_bytes, stream);
  bn_kernel<<<1024, 256, 0, stream>>>(x, bn_w, bn_b, xn);
  for (int s = 0; s < NSTEP + 3; ++s) {
    p.s = s;
    step_kernel<<<960, 256, 0, stream>>>(p);
  }
}